// Round 15
// baseline (977.669 us; speedup 1.0000x reference)
//
#include <hip/hip_runtime.h>
#include <math.h>

#define BATCH   64
#define SEQLEN  128
#define EMBED   512
#define HID     1024
#define NSTEP   127
#define OUT0    65
#define NOUT    62

typedef unsigned short ushort_t;
typedef __attribute__((ext_vector_type(8))) __bf16 bf16x8;
typedef __attribute__((ext_vector_type(4))) float  f32x4;

__device__ __forceinline__ float sigmoidf_(float x) { return 1.f / (1.f + expf(-x)); }

__device__ __forceinline__ ushort_t f2bf(float f) {
    unsigned u = __builtin_bit_cast(unsigned, f);
    unsigned r = (u + 0x7FFFu + ((u >> 16) & 1u)) >> 16;   // round-to-nearest-even
    return (ushort_t)r;
}
__device__ __forceinline__ float bf2f(ushort_t s) {
    unsigned u = ((unsigned)s) << 16;
    return __builtin_bit_cast(float, u);
}

// ===================== MFMA path prep =====================

__global__ __launch_bounds__(256) void init_mfma(
    const float* __restrict__ h0, const float* __restrict__ c0,
    float* __restrict__ cT, ushort_t* __restrict__ hf_hi, ushort_t* __restrict__ hf_lo)
{
    int id = blockIdx.x * 256 + threadIdx.x;   // u*64+b
    int u = id >> 6, b = id & 63;
    cT[id] = c0[b * HID + u];
    float h = h0[b * HID + u];
    ushort_t hs = f2bf(h);
    ushort_t ls = f2bf(h - bf2f(hs));
    size_t idx = (((size_t)(u >> 5)) * 4 + (b >> 4)) * 512
               + ((((u & 31) >> 3) * 16) + (b & 15)) * 8 + (u & 7);
    hf_hi[idx] = hs;
    hf_lo[idx] = ls;
}

// coalesced: thread = (b, k-block-of-8); two 16B bf16x8 stores per element set.
// r15 FIX: r14 dropped the stride loop when splitting into 4 blocks per t —
// each block covered only 256 of its 1024 elements (3/4 of xf left poisoned).
// Restored: 4 elements per thread.
__global__ __launch_bounds__(256) void embed_frag(
    const int* __restrict__ prob, const float* __restrict__ embed,
    ushort_t* __restrict__ xf_hi, ushort_t* __restrict__ xf_lo)
{
    int t  = blockIdx.x >> 2;
    int qd = blockIdx.x & 3;
    if (t >= NSTEP) return;
    #pragma unroll
    for (int i = 0; i < 4; ++i) {
        int e = qd * 1024 + threadIdx.x + i * 256;   // covers qd*1024 .. qd*1024+1023
        int b  = e >> 6;         // 0..63
        int kb = e & 63;         // k-block of 8
        int k  = kb * 8;
        int tok = prob[b * SEQLEN + t];
        const float* row = embed + (size_t)tok * EMBED + k;
        float4 f0 = *(const float4*)(row);
        float4 f1 = *(const float4*)(row + 4);
        float fv[8] = { f0.x, f0.y, f0.z, f0.w, f1.x, f1.y, f1.z, f1.w };
        bf16x8 hv, lv;
        #pragma unroll
        for (int j = 0; j < 8; ++j) {
            ushort_t hs = f2bf(fv[j]);
            ushort_t ls = f2bf(fv[j] - bf2f(hs));
            hv[j] = __builtin_bit_cast(__bf16, hs);
            lv[j] = __builtin_bit_cast(__bf16, ls);
        }
        size_t idx = (((size_t)t * 16 + (kb >> 2)) * 4 + (b >> 4)) * 512
                   + (((kb & 3) * 16) + (b & 15)) * 8;
        *(bf16x8*)(xf_hi + idx) = hv;
        *(bf16x8*)(xf_lo + idx) = lv;
    }
}

// ===================== MFMA persistent kernel (r15 = r14 sync, fixed prep) ===
// 256 blocks x 1024 thr (1 block/CU, 16 waves). Block = 4 units = 16 gate-rows
// (MFMA M-tile). Wave w: N-tile wn=w&3, K-quarter kq=w>>2. bf16x3 math.
// Sync: slice s = bid>>6 (64 producer blocks -> h units s*256..+255, consumed
// by waves with kq==s). Arrivals: 8 stripes x 8 blocks per slice, posted by
// each kq0 wave (lane 0) after per-wave vmcnt drain -- no block barrier
// pre-arrive, no super-counter, no go flag. Consumers poll the 8 stripe
// counters lane-parallel + ballot. Slowest block gates only 1/4 of the work.
__global__ __launch_bounds__(1024) void lstm_mfma(
    const ushort_t* __restrict__ xf_hi, const ushort_t* __restrict__ xf_lo,
    ushort_t* __restrict__ hf_hi, ushort_t* __restrict__ hf_lo,
    const float* __restrict__ cT,
    const float* __restrict__ w_ih, const float* __restrict__ w_hh,
    const float* __restrict__ b_ih, const float* __restrict__ b_hh,
    const float* __restrict__ w_ans, float* __restrict__ pout,
    int* __restrict__ bar)
{
    extern __shared__ ushort_t smem[];
    ushort_t* a_hi = smem;                       // [ks 48][512] 48 KB
    ushort_t* a_lo = smem + 48 * 512;            // 48 KB
    float*    redA = (float*)(smem + 96 * 512);  // 8 KB
    float*    redB = redA + 2048;                // 4 KB

    const int tid = threadIdx.x;
    const int bid = blockIdx.x;
    const int w   = tid >> 6;        // 0..15
    const int wn  = w & 3;           // N-tile
    const int kq  = w >> 2;          // K-quarter 0..3
    const int L   = tid & 63;
    const int n   = L & 15;
    const int q   = L >> 4;
    const int u0  = bid * 4;
    const int ug  = u0 + q;
    const int bg  = wn * 16 + n;

    // arrive line for this block's slice; poll lines for this wave's kq slice
    int* myArrive  = bar + (bid >> 6) * 256 + (bid & 7) * 32;
    int* pollBase  = bar + kq * 256;

    // ---- one-time: weight split -> A-frag LDS image ----
    for (int m = 0; m < 16; ++m) {
        int unit = m >> 2, gate = m & 3;
        size_t rowg = (size_t)gate * HID + u0 + unit;
        for (int k = tid; k < 1536; k += 1024) {
            float f = (k < EMBED) ? w_ih[rowg * EMBED + k]
                                  : w_hh[rowg * HID + (k - EMBED)];
            ushort_t hs = f2bf(f);
            ushort_t ls = f2bf(f - bf2f(hs));
            int off = (k >> 5) * 512 + (((k & 31) >> 3) * 16 + m) * 8 + (k & 7);
            a_hi[off] = hs;
            a_lo[off] = ls;
        }
    }

    float c = cT[ug * 64 + bg];
    float bs[4];
    #pragma unroll
    for (int j = 0; j < 4; ++j) bs[j] = b_ih[j * HID + ug] + b_hh[j * HID + ug];
    const float wansu = w_ans[ug];
    __syncthreads();

    for (int t = 0; t < NSTEP; ++t) {
        f32x4 acc = {0.f, 0.f, 0.f, 0.f};

        // ---- x phase: this wave's 4 ksteps (independent of h(t-1)) ----
        {
            const ushort_t* xh = xf_hi + (((size_t)t * 16 + kq * 4) * 4 + wn) * 512 + L * 8;
            const ushort_t* xl = xf_lo + (((size_t)t * 16 + kq * 4) * 4 + wn) * 512 + L * 8;
            bf16x8 bh = *(const bf16x8*)(xh);
            bf16x8 bl = *(const bf16x8*)(xl);
            #pragma unroll
            for (int ks = 0; ks < 4; ++ks) {
                bf16x8 bh1, bl1;
                if (ks < 3) {
                    bh1 = *(const bf16x8*)(xh + (size_t)(ks + 1) * 2048);
                    bl1 = *(const bf16x8*)(xl + (size_t)(ks + 1) * 2048);
                }
                bf16x8 ah = *(const bf16x8*)(a_hi + (kq * 4 + ks) * 512 + L * 8);
                bf16x8 al = *(const bf16x8*)(a_lo + (kq * 4 + ks) * 512 + L * 8);
                acc = __builtin_amdgcn_mfma_f32_16x16x32_bf16(ah, bh, acc, 0, 0, 0);
                acc = __builtin_amdgcn_mfma_f32_16x16x32_bf16(al, bh, acc, 0, 0, 0);
                acc = __builtin_amdgcn_mfma_f32_16x16x32_bf16(ah, bl, acc, 0, 0, 0);
                bh = bh1; bl = bl1;
            }
        }

        // ---- per-wave wait: this wave's kq slice producers (lane-parallel) ----
        if (t > 0) {
            const int target = 32 * t;      // 4 waves x 8 blocks per stripe, cumulative
            for (;;) {
                int v = __hip_atomic_load(pollBase + (L & 7) * 32,
                                          __ATOMIC_RELAXED, __HIP_MEMORY_SCOPE_AGENT);
                if (__ballot(v >= target) == ~0ULL) break;
                __builtin_amdgcn_s_sleep(1);
            }
            __builtin_amdgcn_fence(__ATOMIC_ACQUIRE, "workgroup");  // no cache inv
        }

        // ---- h phase: this wave's 8 ksteps, 1-deep prefetch ----
        {
            const ushort_t* hh = hf_hi + (((size_t)t * 32 + kq * 8) * 4 + wn) * 512 + L * 8;
            const ushort_t* hl = hf_lo + (((size_t)t * 32 + kq * 8) * 4 + wn) * 512 + L * 8;
            bf16x8 bh = *(const bf16x8*)(hh);
            bf16x8 bl = *(const bf16x8*)(hl);
            #pragma unroll
            for (int ks = 0; ks < 8; ++ks) {
                bf16x8 bh1, bl1;
                if (ks < 7) {
                    bh1 = *(const bf16x8*)(hh + (size_t)(ks + 1) * 2048);
                    bl1 = *(const bf16x8*)(hl + (size_t)(ks + 1) * 2048);
                }
                bf16x8 ah = *(const bf16x8*)(a_hi + (16 + kq * 8 + ks) * 512 + L * 8);
                bf16x8 al = *(const bf16x8*)(a_lo + (16 + kq * 8 + ks) * 512 + L * 8);
                acc = __builtin_amdgcn_mfma_f32_16x16x32_bf16(ah, bh, acc, 0, 0, 0);
                acc = __builtin_amdgcn_mfma_f32_16x16x32_bf16(al, bh, acc, 0, 0, 0);
                acc = __builtin_amdgcn_mfma_f32_16x16x32_bf16(ah, bl, acc, 0, 0, 0);
                bh = bh1; bl = bl1;
            }
        }

        // ---- K reduce: kq>=2 -> REDA; kq<2 add; kq1 -> REDB; kq0 adds ----
        if (kq >= 2)
            *(f32x4*)(redA + ((w - 8) * 64 + L) * 4) = acc;
        __syncthreads();                                   // S1
        if (kq < 2) {
            f32x4 r = *(const f32x4*)(redA + (w * 64 + L) * 4);
            acc += r;
        }
        if (kq == 1)
            *(f32x4*)(redB + ((w - 4) * 64 + L) * 4) = acc;
        __syncthreads();                                   // S2

        if (kq == 0) {
            f32x4 r = *(const f32x4*)(redB + (w * 64 + L) * 4);
            acc += r;

            // ---- finalize in-lane: lane owns (unit ug, batch bg) ----
            float ig = sigmoidf_(acc[0] + bs[0]);
            float fg = sigmoidf_(acc[1] + bs[1]);
            float gg = tanhf    (acc[2] + bs[2]);
            float og = sigmoidf_(acc[3] + bs[3]);
            c = fg * c + ig * gg;
            float h_new = og * tanhf(c);

            float p = h_new * wansu;
            p += __shfl_xor(p, 16, 64);
            p += __shfl_xor(p, 32, 64);
            if (t >= OUT0 && q == 0)
                pout[((size_t)(t - OUT0) * 256 + bid) * 64 + bg] = p;

            ushort_t hs = f2bf(h_new);
            ushort_t ls = f2bf(h_new - bf2f(hs));
            int kr = ug & 31, hks = ug >> 5;
            size_t idx = (((size_t)(t + 1) * 32 + hks) * 4 + wn) * 512
                       + (((kr >> 3) * 16) + n) * 8 + (kr & 7);
            __hip_atomic_store(&hf_hi[idx], hs, __ATOMIC_RELAXED,
                               __HIP_MEMORY_SCOPE_AGENT);
            __hip_atomic_store(&hf_lo[idx], ls, __ATOMIC_RELAXED,
                               __HIP_MEMORY_SCOPE_AGENT);

            // ---- arrive: per-wave drain, lane 0 posts (no block barrier) ----
            if (t < NSTEP - 1) {
                asm volatile("s_waitcnt vmcnt(0)" ::: "memory");
                if (L == 0)
                    __hip_atomic_fetch_add(myArrive, 1, __ATOMIC_RELAXED,
                                           __HIP_MEMORY_SCOPE_AGENT);
            }
        }
    }
}

// out[b][col] = sum over 256 block partials + bias.
__global__ __launch_bounds__(256) void finalize_mfma(
    const float* __restrict__ pout, const float* __restrict__ b_ans,
    float* __restrict__ out)
{
    __shared__ float r[256];
    int col = blockIdx.x;
    int tid = threadIdx.x;
    int b = tid & 63, qq = tid >> 6;
    float s = 0.f;
    for (int i = qq; i < 256; i += 4)
        s += pout[((size_t)col * 256 + i) * 64 + b];
    r[tid] = s;
    __syncthreads();
    if (tid < 64)
        out[tid * NOUT + col] = r[tid] + r[64 + tid] + r[128 + tid] + r[192 + tid]
                              + b_ans[0];
}

// ===================== round-9 proven fallback path =====================
#define NBLK    512
#define NTHR    512
#define REDA_OFF 12288
#define REDB_OFF 14336
#define REDC_OFF 15360
#define C_OFF    15872
#define HEAD_OFF 16000
#define LDS_FLOATS 16128

__global__ __launch_bounds__(256) void init_state(
    const float* __restrict__ h0, const float* __restrict__ c0,
    float* __restrict__ hT, float* __restrict__ cT)
{
    int id = blockIdx.x * 256 + threadIdx.x;
    int u = id >> 6, b = id & 63;
    hT[id] = h0[b * HID + u];
    cT[id] = c0[b * HID + u];
}

__global__ __launch_bounds__(256) void embed_transpose(
    const int* __restrict__ prob, const float* __restrict__ embed,
    float* __restrict__ xT)
{
    __shared__ float xe[64 * 132];
    int t = blockIdx.x;
    int tid = threadIdx.x;
    for (int kt = 0; kt < 4; ++kt) {
        #pragma unroll
        for (int i = 0; i < 8; ++i) {
            int id = tid + i * 256;
            int b  = id >> 5;
            int k4 = id & 31;
            int tok = prob[b * SEQLEN + t];
            float4 v = *(const float4*)(embed + (size_t)tok * EMBED + kt * 128 + k4 * 4);
            *(float4*)(&xe[b * 132 + k4 * 4]) = v;
        }
        __syncthreads();
        #pragma unroll
        for (int i = 0; i < 8; ++i) {
            int id = tid + i * 256;
            int kl = id >> 4;
            int b4 = id & 15;
            float4 v;
            v.x = xe[(b4 * 4 + 0) * 132 + kl];
            v.y = xe[(b4 * 4 + 1) * 132 + kl];
            v.z = xe[(b4 * 4 + 2) * 132 + kl];
            v.w = xe[(b4 * 4 + 3) * 132 + kl];
            *(float4*)(&xT[((size_t)t * EMBED + kt * 128 + kl) * 64 + b4 * 4]) = v;
        }
        __syncthreads();
    }
}

__global__ __launch_bounds__(NTHR, 4) void lstm_persist_hist(
    const float* __restrict__ xT, float* __restrict__ h_hist,
    const float* __restrict__ cT,
    const float* __restrict__ w_ih, const float* __restrict__ w_hh,
    const float* __restrict__ b_ih, const float* __restrict__ b_hh,
    const float* __restrict__ w_ans, float* __restrict__ pout,
    int* __restrict__ bar)
{
    __shared__ float lds[LDS_FLOATS];
    const int tid = threadIdx.x;
    const int bid = blockIdx.x;
    const int b   = tid & 63;
    const int ksl = __builtin_amdgcn_readfirstlane(tid >> 6);
    const int u0  = bid * 2;

    int* sliceCnt = bar + (bid >> 6) * 32;
    int* mySlice  = bar + 256 + (bid >> 6) * 32;
    int* waitGo   = bar + 256 + ksl * 32;

    for (int idx = tid; idx < 12288; idx += NTHR) {
        int r  = idx / 1536;
        int k  = idx - r * 1536;
        int u2 = r & 1, gate = r >> 1;
        int row = gate * HID + u0 + u2;
        float v = (k < EMBED) ? w_ih[(size_t)row * EMBED + k]
                              : w_hh[(size_t)row * HID + (k - EMBED)];
        lds[(u2 * 1536 + k) * 4 + gate] = v;
    }
    if (tid < 128) lds[C_OFF + tid] = cT[u0 * 64 + tid];

    float bias[2][4], wans[2];
    #pragma unroll
    for (int uu = 0; uu < 2; ++uu) {
        #pragma unroll
        for (int j = 0; j < 4; ++j) {
            int rj = j * HID + u0 + uu;
            bias[uu][j] = b_ih[rj] + b_hh[rj];
        }
        wans[uu] = w_ans[u0 + uu];
    }
    __syncthreads();

    for (int t = 0; t < NSTEP; ++t) {
        const float* xt = xT + (size_t)t * EMBED * 64;
        const float* ht = h_hist + (size_t)t * HID * 64;
        float* hn_buf   = h_hist + (size_t)(t + 1) * HID * 64;

        float acc[2][4];
        #pragma unroll
        for (int uu = 0; uu < 2; ++uu)
            #pragma unroll
            for (int j = 0; j < 4; ++j) acc[uu][j] = 0.f;

        const int kx0 = ksl * 64;
        #pragma unroll 4
        for (int g = 0; g < 16; ++g) {
            const int k = kx0 + g * 4;
            float xv[4];
            #pragma unroll
            for (int i = 0; i < 4; ++i) xv[i] = xt[(size_t)(k + i) * 64 + b];
            #pragma unroll
            for (int i = 0; i < 4; ++i) {
                float4 wa = *(const float4*)&lds[(0 * 1536 + k + i) * 4];
                float4 wb = *(const float4*)&lds[(1 * 1536 + k + i) * 4];
                acc[0][0] = fmaf(wa.x, xv[i], acc[0][0]);
                acc[0][1] = fmaf(wa.y, xv[i], acc[0][1]);
                acc[0][2] = fmaf(wa.z, xv[i], acc[0][2]);
                acc[0][3] = fmaf(wa.w, xv[i], acc[0][3]);
                acc[1][0] = fmaf(wb.x, xv[i], acc[1][0]);
                acc[1][1] = fmaf(wb.y, xv[i], acc[1][1]);
                acc[1][2] = fmaf(wb.z, xv[i], acc[1][2]);
                acc[1][3] = fmaf(wb.w, xv[i], acc[1][3]);
            }
        }

        if (t > 0) {
            while (__hip_atomic_load(waitGo, __ATOMIC_RELAXED,
                                     __HIP_MEMORY_SCOPE_AGENT) < t)
                __builtin_amdgcn_s_sleep(4);
            __builtin_amdgcn_fence(__ATOMIC_ACQUIRE, "workgroup");
        }

        const int kh0 = ksl * 128;
        #pragma unroll 4
        for (int g = 0; g < 32; ++g) {
            const int kh = kh0 + g * 4;
            float hv[4];
            #pragma unroll
            for (int i = 0; i < 4; ++i)
                hv[i] = ht[(size_t)(kh + i) * 64 + b];
            #pragma unroll
            for (int i = 0; i < 4; ++i) {
                const int kw = EMBED + kh + i;
                float4 wa = *(const float4*)&lds[(0 * 1536 + kw) * 4];
                float4 wb = *(const float4*)&lds[(1 * 1536 + kw) * 4];
                acc[0][0] = fmaf(wa.x, hv[i], acc[0][0]);
                acc[0][1] = fmaf(wa.y, hv[i], acc[0][1]);
                acc[0][2] = fmaf(wa.z, hv[i], acc[0][2]);
                acc[0][3] = fmaf(wa.w, hv[i], acc[0][3]);
                acc[1][0] = fmaf(wb.x, hv[i], acc[1][0]);
                acc[1][1] = fmaf(wb.y, hv[i], acc[1][1]);
                acc[1][2] = fmaf(wb.z, hv[i], acc[1][2]);
                acc[1][3] = fmaf(wb.w, hv[i], acc[1][3]);
            }
        }

        if (ksl >= 4) {
            #pragma unroll
            for (int uu = 0; uu < 2; ++uu)
                #pragma unroll
                for (int j = 0; j < 4; ++j)
                    lds[REDA_OFF + (((ksl - 4) * 8) + uu * 4 + j) * 64 + b] = acc[uu][j];
        }
        __syncthreads();
        if (ksl < 4) {
            #pragma unroll
            for (int uu = 0; uu < 2; ++uu)
                #pragma unroll
                for (int j = 0; j < 4; ++j)
                    acc[uu][j] += lds[REDA_OFF + ((ksl * 8) + uu * 4 + j) * 64 + b];
        }
        if (ksl == 2 || ksl == 3) {
            #pragma unroll
            for (int uu = 0; uu < 2; ++uu)
                #pragma unroll
                for (int j = 0; j < 4; ++j)
                    lds[REDB_OFF + (((ksl - 2) * 8) + uu * 4 + j) * 64 + b] = acc[uu][j];
        }
        __syncthreads();
        if (ksl < 2) {
            #pragma unroll
            for (int uu = 0; uu < 2; ++uu)
                #pragma unroll
                for (int j = 0; j < 4; ++j)
                    acc[uu][j] += lds[REDB_OFF + ((ksl * 8) + uu * 4 + j) * 64 + b];
        }
        if (ksl == 0) {
            #pragma unroll
            for (int j = 0; j < 4; ++j)
                lds[REDC_OFF + j * 64 + b] = acc[1][j];
        }
        if (ksl == 1) {
            #pragma unroll
            for (int j = 0; j < 4; ++j)
                lds[REDC_OFF + (4 + j) * 64 + b] = acc[0][j];
        }
        __syncthreads();
        if (ksl < 2) {
            const int uu = ksl;
            float s[4];
            if (ksl == 0) {
                #pragma unroll
                for (int j = 0; j < 4; ++j)
                    s[j] = acc[0][j] + lds[REDC_OFF + (4 + j) * 64 + b];
            } else {
                #pragma unroll
                for (int j = 0; j < 4; ++j)
                    s[j] = acc[1][j] + lds[REDC_OFF + j * 64 + b];
            }
            float i_g = sigmoidf_(s[0] + bias[uu][0]);
            float f_g = sigmoidf_(s[1] + bias[uu][1]);
            float g_g = tanhf   (s[2] + bias[uu][2]);
            float o_g = sigmoidf_(s[3] + bias[uu][3]);
            float c_old = lds[C_OFF + uu * 64 + b];
            float c_new = f_g * c_old + i_g * g_g;
            float h_new = o_g * tanhf(c_new);
            lds[C_OFF + uu * 64 + b] = c_new;
            __hip_atomic_store(&hn_buf[(u0 + uu) * 64 + b], h_new,
                               __ATOMIC_RELAXED, __HIP_MEMORY_SCOPE_AGENT);
            lds[HEAD_OFF + uu * 64 + b] = h_new * wans[uu];
        }

        __syncthreads();
        if (t >= OUT0 && tid < 64) {
            pout[((size_t)(t - OUT0) * NBLK + bid) * 64 + tid] =
                lds[HEAD_OFF + tid] + lds[HEAD_OFF + 64 + tid];
        }
        if (t == NSTEP - 1) break;
        if (tid == 0) {
            int r = __hip_atomic_fetch_add(sliceCnt, 1, __ATOMIC_RELAXED,
                                           __HIP_MEMORY_SCOPE_AGENT);
            if (r == 64 * (t + 1) - 1)
                __hip_atomic_store(mySlice, t + 1, __ATOMIC_RELAXED,
                                   __HIP_MEMORY_SCOPE_AGENT);
        }
    }
}

__global__ __launch_bounds__(256) void finalize_persist(
    const float* __restrict__ pout, const float* __restrict__ b_ans,
    float* __restrict__ out)
{
    __shared__ float r[256];
    int col = blockIdx.x;
    int tid = threadIdx.x;
    int b = tid & 63, qq = tid >> 6;
    float s = 0.f;
    for (int i = qq; i < NBLK; i += 4)
        s += pout[((size_t)col * NBLK + i) * 64 + b];
    r[tid] = s;
    __syncthreads();
    if (tid < 64)
        out[tid * NOUT + col] = r[tid] + r[64 + tid] + r[128 + tid] + r[192 + tid]
                              + b_ans[0];
}

extern "C" void kernel_launch(void* const* d_in, const int* in_sizes, int n_in,
                              void* d_out, int out_size, void* d_ws, size_t ws_size,
                              hipStream_t stream)
{
    const int*   prob  = (const int*)  d_in[0];
    const float* embed = (const float*)d_in[2];
    const float* w_ih  = (const float*)d_in[3];
    const float* w_hh  = (const float*)d_in[4];
    const float* b_ih  = (const float*)d_in[5];
    const float* b_hh  = (const float*)d_in[6];
    const float* w_ans = (const float*)d_in[7];
    const float* b_ans = (const float*)d_in[8];
    const float* h0    = (const float*)d_in[9];
    const float* c0    = (const float*)d_in[10];

    // ---- MFMA-path ws layout (bytes) ----
    char* W = (char*)d_ws;
    float*    cT_m  = (float*)   (W);              // 262,144 B
    float*    poutm = (float*)   (W + 262144);     // 4,063,232 B
    ushort_t* xf_hi = (ushort_t*)(W + 4325376);    // 8,323,072 B
    ushort_t* xf_lo = (ushort_t*)(W + 12648448);   // 8,323,072 B
    ushort_t* hf_hi = (ushort_t*)(W + 20971520);   // 16,777,216 B
    ushort_t* hf_lo = (ushort_t*)(W + 37748736);   // 16,777,216 B
    int*      bar_m = (int*)     (W + 54525952);   // 4,096 B (4 slices x 8 stripes)

    const int DYN_LDS = 96 * 1024 + 12288;         // A-frags + redA(8K) + redB(4K)

    hipError_t err = hipFuncSetAttribute(
        (const void*)lstm_mfma,
        hipFuncAttributeMaxDynamicSharedMemorySize, DYN_LDS);

    if (err == hipSuccess) {
        hipMemsetAsync(bar_m, 0, 4096, stream);
        init_mfma<<<256, 256, 0, stream>>>(h0, c0, cT_m, hf_hi, hf_lo);
        embed_frag<<<NSTEP * 4, 256, 0, stream>>>(prob, embed, xf_hi, xf_lo);

        void* args[] = {
            (void*)&xf_hi, (void*)&xf_lo, (void*)&hf_hi, (void*)&hf_lo,
            (void*)&cT_m, (void*)&w_ih, (void*)&w_hh, (void*)&b_ih,
            (void*)&b_hh, (void*)&w_ans, (void*)&poutm, (void*)&bar_m
        };
        err = hipLaunchCooperativeKernel((const void*)lstm_mfma,
                                         dim3(256), dim3(1024),
                                         args, DYN_LDS, stream);
        if (err == hipSuccess) {
            finalize_mfma<<<NOUT, 256, 0, stream>>>(poutm, b_ans, (float*)d_out);
            return;
        }
    }

    // ---- fallback: round-9 proven path (aliases the same ws region) ----
    float* ws     = (float*)d_ws;
    float* cT     = ws;                    // 65,536 fl
    float* pout   = ws + 65536;            // 2,031,616 fl
    float* xT     = ws + 2097152;          // 4,161,536 fl
    float* h_hist = ws + 6258688;          // 8,388,608 fl
    int*   bar    = (int*)(ws + 14647296);

    hipMemsetAsync(bar, 0, 2048, stream);
    init_state<<<256, 256, 0, stream>>>(h0, c0, h_hist, cT);
    embed_transpose<<<NSTEP, 256, 0, stream>>>(prob, embed, xT);

    void* args9[] = {
        (void*)&xT, (void*)&h_hist, (void*)&cT,
        (void*)&w_ih, (void*)&w_hh, (void*)&b_ih, (void*)&b_hh,
        (void*)&w_ans, (void*)&pout, (void*)&bar
    };
    hipLaunchCooperativeKernel((const void*)lstm_persist_hist,
                               dim3(NBLK), dim3(NTHR), args9, 0, stream);
    finalize_persist<<<NOUT, 256, 0, stream>>>(pout, b_ans, (float*)d_out);
}